// Round 12
// baseline (413.995 us; speedup 1.0000x reference)
//
#include <hip/hip_runtime.h>
#include <math.h>

#define DDIM 2048
#define NDIM 8192
#define NTRI8 36   // lower-triangle 256x256 tiles of the 2048x2048 G (8x8 grid)

typedef _Float16 f16;
typedef _Float16 f16x8 __attribute__((ext_vector_type(8)));
typedef _Float16 f16x4 __attribute__((ext_vector_type(4)));
typedef float    f32x4 __attribute__((ext_vector_type(4)));

#define MFMA16(a, b, c) __builtin_amdgcn_mfma_f32_16x16x32_f16(a, b, c, 0, 0, 0)

__device__ __forceinline__ void gload_lds16(const f16* g, f16* l) {
    __builtin_amdgcn_global_load_lds(
        (__attribute__((address_space(1))) const void*)g,
        (__attribute__((address_space(3))) void*)l, 16, 0, 0);
}

// raw barrier (NOT __syncthreads: avoids compiler-inserted vmcnt(0) drain)
#define SBAR() do { __builtin_amdgcn_sched_barrier(0); \
                    __builtin_amdgcn_s_barrier();      \
                    __builtin_amdgcn_sched_barrier(0); } while (0)
#define VMCNT0() asm volatile("s_waitcnt vmcnt(0)" ::: "memory")
#define VMCNT2() asm volatile("s_waitcnt vmcnt(2)" ::: "memory")
#define VMCNT4() asm volatile("s_waitcnt vmcnt(4)" ::: "memory")
#define VMCNT8() asm volatile("s_waitcnt vmcnt(8)" ::: "memory")

// bijective XCD-chunk swizzle (m204): n may be non-multiple of 8
__device__ __forceinline__ int xcd_swz(int lin, int n) {
    const int xcd = lin & 7, pos = lin >> 3;
    const int q = n >> 3, r = n & 7;
    return (xcd < r ? xcd * (q + 1) : r * (q + 1) + (xcd - r) * q) + pos;
}

// ---------------------------------------------------------------------------
// T2 bank-conflict swizzle for the [256 rows][32 f16] LDS unit (64 B rows).
// VALIDATED ONLY for the 16x16-MFMA read pattern (R3..R11: 0 conflicts).
// ---------------------------------------------------------------------------
__device__ __forceinline__ int swz(int R, int fo8) {
    return R * 32 + (fo8 ^ (((R >> 1) & 3) << 3));
}

// stage one 16 KiB unit (256 rows x 32 k-elems, f16) global -> LDS.
// 2 vmem ops per thread. LDS dest linear; source k-slot pre-swizzled.
__device__ __forceinline__ void stage_unit(
    const f16* __restrict__ g, int grow0, size_t kelem, int Ktot,
    f16* ldsbase, int tid)
{
#pragma unroll
    for (int i = 0; i < 2; ++i) {
        const int c = tid + i * 512;
        const int row  = c >> 2;
        const int slot = (c & 3) ^ ((c >> 3) & 3);   // (c&3) ^ ((row>>1)&3)
        gload_lds16(g + (size_t)(grow0 + row) * Ktot + kelem + slot * 8,
                    ldsbase + c * 8);
    }
}

// ---------------------------------------------------------------------------
// K2 (R12): 256x256 FUSED split-fp16 NT GEMM.
// TRI: R10 relaxed-barrier schedule + SOURCE-PINNED read cluster.
//   R11 showed the compiler won't extend liveness on its own (VGPR stayed
//   128); here the region's 20 ds_reads (ah,bh,al) + 3 stages are issued
//   FIRST, a sched_barrier(0) fence stops the scheduler re-sinking them,
//   then 64 MFMAs ordered ah*bh -> al*bh so the al reads (last queued)
//   drain under the earliest MFMAs via counted lgkmcnt.
//   STAGE ISSUE ORDER PER TILE IS IDENTICAL TO R10 (Bh,Ah,Bl in region;
//   Al(u+2) in P3) -> the R10-audited vmcnt ledger carries over verbatim:
//    * region-end vmcnt(8)+SBAR covers Bl(u) (8 ops deep) + gates al ovw.
//    * P3-end vmcnt(4)+SBAR covers Ah/Bh(u+1) (4 deep) and Al(u+1) (9 deep).
//   Liveness ~230 VGPR < 256 -> 2 waves/SIMD kept ((512,1) permits).
// dense: byte-identical to R11 (schedule-hypersensitive; gets this after
//   TRI confirms).
// ---------------------------------------------------------------------------
template <bool TRI>
__global__ __launch_bounds__(512, 1) void gemm8_split(
    const f16* __restrict__ Ah_g, const f16* __restrict__ Al_g,
    const f16* __restrict__ Bh_g, const f16* __restrict__ Bl_g,
    float* __restrict__ C, int Mrows, int Ncols, int Ktot, int Kchunk)
{
    __shared__ f16 lds[65536];   // 128 KiB

    const int tid  = threadIdx.x;
    const int lane = tid & 63;
    const int w    = tid >> 6;
    const int wr   = w >> 2;          // 0..1
    const int wc   = w & 3;           // 0..3
    const int ln15 = lane & 15;
    const int fo8  = (lane >> 4) * 8;

    int row0, col0, nkt;
    size_t kbeg;
    if constexpr (TRI) {
        const int t = xcd_swz(blockIdx.x, NTRI8);
        int i = 0;
        while ((i + 1) * (i + 2) / 2 <= t) ++i;
        const int j = t - i * (i + 1) / 2;
        row0 = i * 256; col0 = j * 256;
        const int z = blockIdx.z;                       // 0..6, uneven chunks
        const int kb_u = z * 37 - (z > 4 ? z - 4 : 0);  // 37,37,37,37,36,36,36
        nkt = (z < 4) ? 37 : 36;
        kbeg = (size_t)kb_u * 32;
        C += ((size_t)z * NTRI8 + t) * (256 * 256);     // compact partial
    } else {
        const int s = xcd_swz(blockIdx.y * gridDim.x + blockIdx.x,
                              gridDim.x * gridDim.y);
        row0 = (s / gridDim.x) * 256;
        col0 = (s % gridDim.x) * 256;
        nkt  = Kchunk / 32;
        kbeg = (size_t)blockIdx.z * Kchunk;
        C += (size_t)blockIdx.z * Mrows * Ncols;
    }

    f32x4 acc[8][4] = {};

    // prologue: tile0's 4 units + Al(1); drain; barrier
    stage_unit(Ah_g, row0, kbeg, Ktot, lds + 0,     tid);
    stage_unit(Al_g, row0, kbeg, Ktot, lds + 8192,  tid);
    stage_unit(Bh_g, col0, kbeg, Ktot, lds + 16384, tid);
    stage_unit(Bl_g, col0, kbeg, Ktot, lds + 24576, tid);
    if (nkt > 1)
        stage_unit(Al_g, row0, kbeg + 32, Ktot, lds + 32768 + 8192, tid);
    VMCNT0();
    SBAR();

    for (int u = 0; u < nkt; ++u) {
        const int cur = (u & 1) * 32768, nxt = ((u + 1) & 1) * 32768;
        const size_t ku = kbeg + (size_t)u * 32;

        if constexpr (TRI) {
            f16x8 ah[8], bh[4], al[8];

            // ---- region: ALL reads first (pinned), stages, then 64 MFMAs ----
#pragma unroll
            for (int m = 0; m < 8; ++m)
                ah[m] = *(const f16x8*)&lds[cur + swz(wr * 128 + m * 16 + ln15, fo8)];
#pragma unroll
            for (int n = 0; n < 4; ++n)
                bh[n] = *(const f16x8*)&lds[cur + 16384 + swz(wc * 64 + n * 16 + ln15, fo8)];
#pragma unroll
            for (int m = 0; m < 8; ++m)
                al[m] = *(const f16x8*)&lds[cur + 8192 + swz(wr * 128 + m * 16 + ln15, fo8)];
            if (u + 1 < nkt) {
                stage_unit(Bh_g, col0, ku + 32, Ktot, lds + nxt + 16384, tid);
                stage_unit(Ah_g, row0, ku + 32, Ktot, lds + nxt + 0, tid);
                stage_unit(Bl_g, col0, ku + 32, Ktot, lds + nxt + 24576, tid);
            }
            __builtin_amdgcn_sched_barrier(0);   // fence: reads stay above
            __builtin_amdgcn_s_setprio(1);
#pragma unroll
            for (int m = 0; m < 8; ++m)
#pragma unroll
                for (int n = 0; n < 4; ++n)
                    acc[m][n] = MFMA16(ah[m], bh[n], acc[m][n]);
#pragma unroll
            for (int m = 0; m < 8; ++m)
#pragma unroll
                for (int n = 0; n < 4; ++n)
                    acc[m][n] = MFMA16(al[m], bh[n], acc[m][n]);
            __builtin_amdgcn_s_setprio(0);
            if (u == nkt - 1) { VMCNT0(); } else { VMCNT8(); }
            SBAR();   // KEPT: covers Bl(u) for P3 reads; gates al overwrite

            // ---- P3: HL, all n (ah live; bl post-barrier per ledger) ----
            {
                f16x8 bl[4];
#pragma unroll
                for (int n = 0; n < 4; ++n)
                    bl[n] = *(const f16x8*)&lds[cur + 24576 + swz(wc * 64 + n * 16 + ln15, fo8)];
                if (u + 2 < nkt) stage_unit(Al_g, row0, ku + 64, Ktot, lds + cur + 8192, tid);
                __builtin_amdgcn_sched_barrier(0);
                __builtin_amdgcn_s_setprio(1);
#pragma unroll
                for (int m = 0; m < 8; ++m)
#pragma unroll
                    for (int n = 0; n < 4; ++n)
                        acc[m][n] = MFMA16(ah[m], bl[n], acc[m][n]);
                __builtin_amdgcn_s_setprio(0);
            }
            if (u < nkt - 2) { VMCNT4(); }
            else if (u == nkt - 2) { VMCNT2(); }
            SBAR();   // KEPT: tile boundary; covers Ah/Bh/Al(u+1)
        } else {
            // ================= dense: R11 body, unchanged =================
            f16x8 ah[8], bh[4];

            // ---- P0: HH, n-half 0 (no barrier) ----
#pragma unroll
            for (int m = 0; m < 8; ++m)
                ah[m] = *(const f16x8*)&lds[cur + swz(wr * 128 + m * 16 + ln15, fo8)];
            bh[0] = *(const f16x8*)&lds[cur + 16384 + swz(wc * 64 +  0 + ln15, fo8)];
            bh[1] = *(const f16x8*)&lds[cur + 16384 + swz(wc * 64 + 16 + ln15, fo8)];
            if (u + 1 < nkt) stage_unit(Bh_g, col0, ku + 32, Ktot, lds + nxt + 16384, tid);
            __builtin_amdgcn_s_setprio(1);
#pragma unroll
            for (int m = 0; m < 8; ++m) {
                acc[m][0] = MFMA16(ah[m], bh[0], acc[m][0]);
                acc[m][1] = MFMA16(ah[m], bh[1], acc[m][1]);
            }
            __builtin_amdgcn_s_setprio(0);

            // ---- P1: HH, n-half 1 (no barrier) ----
            bh[2] = *(const f16x8*)&lds[cur + 16384 + swz(wc * 64 + 32 + ln15, fo8)];
            bh[3] = *(const f16x8*)&lds[cur + 16384 + swz(wc * 64 + 48 + ln15, fo8)];
            if (u + 1 < nkt) stage_unit(Ah_g, row0, ku + 32, Ktot, lds + nxt + 0, tid);
            __builtin_amdgcn_s_setprio(1);
#pragma unroll
            for (int m = 0; m < 8; ++m) {
                acc[m][2] = MFMA16(ah[m], bh[2], acc[m][2]);
                acc[m][3] = MFMA16(ah[m], bh[3], acc[m][3]);
            }
            __builtin_amdgcn_s_setprio(0);

            // ---- P2: LH, all n ----
            {
                f16x8 al[8];
#pragma unroll
                for (int m = 0; m < 8; ++m)
                    al[m] = *(const f16x8*)&lds[cur + 8192 + swz(wr * 128 + m * 16 + ln15, fo8)];
                if (u + 1 < nkt) stage_unit(Bl_g, col0, ku + 32, Ktot, lds + nxt + 24576, tid);
                __builtin_amdgcn_s_setprio(1);
#pragma unroll
                for (int m = 0; m < 8; ++m)
#pragma unroll
                    for (int n = 0; n < 4; ++n)
                        acc[m][n] = MFMA16(al[m], bh[n], acc[m][n]);
                __builtin_amdgcn_s_setprio(0);
            }
            if (u == nkt - 1) { VMCNT0(); } else { VMCNT8(); }
            SBAR();

            // ---- P3: HL, all n (a2 re-read) ----
            {
                f16x8 a2[8], bl[4];
#pragma unroll
                for (int m = 0; m < 8; ++m)
                    a2[m] = *(const f16x8*)&lds[cur + swz(wr * 128 + m * 16 + ln15, fo8)];
#pragma unroll
                for (int n = 0; n < 4; ++n)
                    bl[n] = *(const f16x8*)&lds[cur + 24576 + swz(wc * 64 + n * 16 + ln15, fo8)];
                if (u + 2 < nkt) stage_unit(Al_g, row0, ku + 64, Ktot, lds + cur + 8192, tid);
                __builtin_amdgcn_s_setprio(1);
#pragma unroll
                for (int m = 0; m < 8; ++m)
#pragma unroll
                    for (int n = 0; n < 4; ++n)
                        acc[m][n] = MFMA16(a2[m], bl[n], acc[m][n]);
                __builtin_amdgcn_s_setprio(0);
            }
            if (u < nkt - 2) { VMCNT4(); }
            else if (u == nkt - 2) { VMCNT2(); }
            SBAR();
        }
    }

    // epilogue: C/D layout col=lane&15, row=(lane>>4)*4+reg [m89-verified]
    const int rsub = (lane >> 4) * 4;
#pragma unroll
    for (int m = 0; m < 8; ++m)
#pragma unroll
        for (int n = 0; n < 4; ++n)
#pragma unroll
            for (int r = 0; r < 4; ++r) {
                const int cr = wr * 128 + m * 16 + rsub + r;
                const int cc = wc * 64 + n * 16 + ln15;
                if constexpr (TRI)
                    C[(size_t)cr * 256 + cc] = acc[m][n][r];
                else
                    C[(size_t)(row0 + cr) * Ncols + col0 + cc] = acc[m][n][r];
            }
}

// ---------------------------------------------------------------------------
// K1 (R12): 256x256 single-product NT GEMM, BK=64 -- R11 body, unchanged
// (relaxed barriers p1-end/p3-end + (512,1)).
// ---------------------------------------------------------------------------
__global__ __launch_bounds__(512, 1) void gemm8_nt(
    const f16* __restrict__ A_g, const f16* __restrict__ B_g,
    float* __restrict__ C, int Mrows, int Ncols, int Ktot, int Kchunk)
{
    __shared__ f16 lds[65536];

    const int tid  = threadIdx.x;
    const int lane = tid & 63;
    const int w    = tid >> 6;
    const int wr   = w >> 2;
    const int wc   = w & 3;
    const int ln15 = lane & 15;
    const int fo8  = (lane >> 4) * 8;

    const int s = xcd_swz(blockIdx.y * gridDim.x + blockIdx.x,
                          gridDim.x * gridDim.y);
    const int row0 = (s / gridDim.x) * 256;
    const int col0 = (s % gridDim.x) * 256;
    const int nkt  = Kchunk / 64;
    const size_t kbeg = (size_t)blockIdx.z * Kchunk;
    C += (size_t)blockIdx.z * Mrows * Ncols;

    f32x4 acc[8][4] = {};

    stage_unit(A_g, row0, kbeg,      Ktot, lds + 0,     tid);  // Ak0(0)
    stage_unit(B_g, col0, kbeg,      Ktot, lds + 16384, tid);  // Bk0(0)
    stage_unit(A_g, row0, kbeg + 32, Ktot, lds + 8192,  tid);  // Ak1(0)
    stage_unit(B_g, col0, kbeg + 32, Ktot, lds + 24576, tid);  // Bk1(0)
    VMCNT0();
    SBAR();

    for (int u = 0; u < nkt; ++u) {
        const int cur = (u & 1) * 32768, nxt = ((u + 1) & 1) * 32768;
        const size_t ku = kbeg + (size_t)u * 64;
        f16x8 a[8], b0, b1;

        // ---- p0: ks0, n-half 0 (no barrier) ----
#pragma unroll
        for (int m = 0; m < 8; ++m)
            a[m] = *(const f16x8*)&lds[cur + swz(wr * 128 + m * 16 + ln15, fo8)];
        b0 = *(const f16x8*)&lds[cur + 16384 + swz(wc * 64 +  0 + ln15, fo8)];
        b1 = *(const f16x8*)&lds[cur + 16384 + swz(wc * 64 + 16 + ln15, fo8)];
        if (u + 1 < nkt) stage_unit(A_g, row0, ku + 64, Ktot, lds + nxt + 0, tid);
        __builtin_amdgcn_s_setprio(1);
#pragma unroll
        for (int m = 0; m < 8; ++m) {
            acc[m][0] = MFMA16(a[m], b0, acc[m][0]);
            acc[m][1] = MFMA16(a[m], b1, acc[m][1]);
        }
        __builtin_amdgcn_s_setprio(0);

        // ---- p1: ks0, n-half 1 ----
        b0 = *(const f16x8*)&lds[cur + 16384 + swz(wc * 64 + 32 + ln15, fo8)];
        b1 = *(const f16x8*)&lds[cur + 16384 + swz(wc * 64 + 48 + ln15, fo8)];
        if (u + 1 < nkt) stage_unit(B_g, col0, ku + 64, Ktot, lds + nxt + 16384, tid);
        __builtin_amdgcn_s_setprio(1);
#pragma unroll
        for (int m = 0; m < 8; ++m) {
            acc[m][2] = MFMA16(a[m], b0, acc[m][2]);
            acc[m][3] = MFMA16(a[m], b1, acc[m][3]);
        }
        __builtin_amdgcn_s_setprio(0);
        if (u == nkt - 1) { VMCNT0(); } else { VMCNT4(); }
        SBAR();   // KEPT: covers Ak1/Bk1(u) for p2/p3 reads

        // ---- p2: ks1, n-half 0 (no barrier) ----
#pragma unroll
        for (int m = 0; m < 8; ++m)
            a[m] = *(const f16x8*)&lds[cur + 8192 + swz(wr * 128 + m * 16 + ln15, fo8)];
        b0 = *(const f16x8*)&lds[cur + 24576 + swz(wc * 64 +  0 + ln15, fo8)];
        b1 = *(const f16x8*)&lds[cur + 24576 + swz(wc * 64 + 16 + ln15, fo8)];
        if (u + 1 < nkt) stage_unit(A_g, row0, ku + 96, Ktot, lds + nxt + 8192, tid);
        __builtin_amdgcn_s_setprio(1);
#pragma unroll
        for (int m = 0; m < 8; ++m) {
            acc[m][0] = MFMA16(a[m], b0, acc[m][0]);
            acc[m][1] = MFMA16(a[m], b1, acc[m][1]);
        }
        __builtin_amdgcn_s_setprio(0);

        // ---- p3: ks1, n-half 1 ----
        b0 = *(const f16x8*)&lds[cur + 24576 + swz(wc * 64 + 32 + ln15, fo8)];
        b1 = *(const f16x8*)&lds[cur + 24576 + swz(wc * 64 + 48 + ln15, fo8)];
        if (u + 1 < nkt) stage_unit(B_g, col0, ku + 96, Ktot, lds + nxt + 24576, tid);
        __builtin_amdgcn_s_setprio(1);
#pragma unroll
        for (int m = 0; m < 8; ++m) {
            acc[m][2] = MFMA16(a[m], b0, acc[m][2]);
            acc[m][3] = MFMA16(a[m], b1, acc[m][3]);
        }
        __builtin_amdgcn_s_setprio(0);
        if (u < nkt - 1) { VMCNT4(); }
        SBAR();   // KEPT: tile boundary; covers Ak0/Bk0(u+1)
    }

    const int rsub = (lane >> 4) * 4;
#pragma unroll
    for (int m = 0; m < 8; ++m)
#pragma unroll
        for (int n = 0; n < 4; ++n)
#pragma unroll
            for (int r = 0; r < 4; ++r)
                C[(size_t)(row0 + wr * 128 + m * 16 + rsub + r) * Ncols
                  + col0 + wc * 64 + n * 16 + ln15] = acc[m][n][r];
}

// ---------------------------------------------------------------------------
// split BOTH W matrices fp32 -> fp16 hi/lo in one launch
// ---------------------------------------------------------------------------
__global__ __launch_bounds__(256) void split_w2(
    const float* __restrict__ A, const float* __restrict__ B,
    f16* __restrict__ Ahi, f16* __restrict__ Alo,
    f16* __restrict__ Bhi, f16* __restrict__ Blo, long n4)
{
    long i = (long)blockIdx.x * 256 + threadIdx.x;
    const float* src;
    f16 *hi, *lo;
    long k;
    if (i < n4) { src = A; hi = Ahi; lo = Alo; k = i; }
    else        { src = B; hi = Bhi; lo = Blo; k = i - n4; }
    float4 x = ((const float4*)src)[k];
    float a = x.x, b = x.y, c = x.z, d = x.w;
    f16x4 h;
    h[0] = (f16)a; h[1] = (f16)b; h[2] = (f16)c; h[3] = (f16)d;
    ((f16x4*)hi)[k] = h;
    f16x4 l;
    l[0] = (f16)(a - (float)h[0]);
    l[1] = (f16)(b - (float)h[1]);
    l[2] = (f16)(c - (float)h[2]);
    l[3] = (f16)(d - (float)h[3]);
    ((f16x4*)lo)[k] = l;
}

// ---------------------------------------------------------------------------
// fused split fp32 -> f16 hi/lo (row-major) + hi^T, 64x64 tiles.
// ---------------------------------------------------------------------------
__global__ __launch_bounds__(256) void split_xt(
    const float* __restrict__ in, f16* __restrict__ hi, f16* __restrict__ lo,
    f16* __restrict__ hiT, int rows, int cols)
{
    __shared__ f16 tile[64][72];
    const int c0 = blockIdx.x * 64;
    const int r0 = blockIdx.y * 64;
    const int t = threadIdx.x;
    const int lr = t >> 3;      // 0..31
    const int lc8 = t & 7;      // 0..7
#pragma unroll
    for (int h = 0; h < 2; ++h) {
        const int r = lr + h * 32;
        const float* src = &in[(size_t)(r0 + r) * cols + c0 + lc8 * 8];
        float4 a = ((const float4*)src)[0];
        float4 b = ((const float4*)src)[1];
        float v[8] = {a.x, a.y, a.z, a.w, b.x, b.y, b.z, b.w};
        f16x8 hv, lv;
#pragma unroll
        for (int j = 0; j < 8; ++j) {
            hv[j] = (f16)v[j];
            lv[j] = (f16)(v[j] - (float)hv[j]);
        }
        *(f16x8*)&hi[(size_t)(r0 + r) * cols + c0 + lc8 * 8] = hv;
        if (lo != nullptr)
            *(f16x8*)&lo[(size_t)(r0 + r) * cols + c0 + lc8 * 8] = lv;
#pragma unroll
        for (int j = 0; j < 8; ++j) tile[r][lc8 * 8 + j] = hv[j];
    }
    __syncthreads();
#pragma unroll
    for (int h = 0; h < 2; ++h) {
        const int c = lr + h * 32;
        f16x8 v;
#pragma unroll
        for (int j = 0; j < 8; ++j) v[j] = tile[lc8 * 8 + j][c];
        *(f16x8*)&hiT[(size_t)(c0 + c) * rows + r0 + lc8 * 8] = v;
    }
}

// ---------------------------------------------------------------------------
// reduce 4 contiguous fp32 partials -> fp16 hi/lo (lo may be null), scaled
// ---------------------------------------------------------------------------
__global__ __launch_bounds__(256) void reduce4_split(
    const float* __restrict__ P, f16* __restrict__ hi, f16* __restrict__ lo,
    long n4, float scale)
{
    long i = (long)blockIdx.x * 256 + threadIdx.x;
    if (i >= n4) return;
    const float4* p = (const float4*)P;
    float4 a = p[i], b = p[i + n4], c = p[i + 2 * n4], d = p[i + 3 * n4];
    float v0 = ((a.x + b.x) + (c.x + d.x)) * scale;
    float v1 = ((a.y + b.y) + (c.y + d.y)) * scale;
    float v2 = ((a.z + b.z) + (c.z + d.z)) * scale;
    float v3 = ((a.w + b.w) + (c.w + d.w)) * scale;
    f16x4 h;
    h[0] = (f16)v0; h[1] = (f16)v1; h[2] = (f16)v2; h[3] = (f16)v3;
    ((f16x4*)hi)[i] = h;
    if (lo != nullptr) {
        f16x4 l;
        l[0] = (f16)(v0 - (float)h[0]);
        l[1] = (f16)(v1 - (float)h[1]);
        l[2] = (f16)(v2 - (float)h[2]);
        l[3] = (f16)(v3 - (float)h[3]);
        ((f16x4*)lo)[i] = l;
    }
}

// ---------------------------------------------------------------------------
// reduce 7 compact 256x256 triangle partials -> Ghi/Glo at tile (i,j)
// AND mirror to (j,i) when i>j (fused symm). grid (16, NTRI8): block = one
// 64x64 subtile (4x4 per 256-tile); LDS transpose for the mirror.
// ---------------------------------------------------------------------------
__global__ __launch_bounds__(256) void reduce7s(
    const float* __restrict__ P, f16* __restrict__ hi, f16* __restrict__ lo)
{
    const int t = blockIdx.y;
    int i = 0;
    while ((i + 1) * (i + 2) / 2 <= t) ++i;
    const int j = t - i * (i + 1) / 2;
    const int r0 = (blockIdx.x >> 2) * 64;   // subtile origin within 256-tile
    const int c0 = (blockIdx.x & 3) * 64;

    const int tid = threadIdx.x;
    const int lr = tid >> 2;                 // 0..63
    const int lc = (tid & 3) * 16;           // 0,16,32,48

    const long zs = (long)NTRI8 * (256 * 256);  // slice stride (floats)
    const float* q = P + (long)t * (256 * 256)
                   + (size_t)(r0 + lr) * 256 + c0 + lc;

    __shared__ f16 th[64][72], tl[64][72];

    float v[16];
#pragma unroll
    for (int e = 0; e < 16; ++e) v[e] = 0.f;
#pragma unroll
    for (int z = 0; z < 7; ++z) {
        const float4* qz = (const float4*)(q + z * zs);
#pragma unroll
        for (int w4 = 0; w4 < 4; ++w4) {
            float4 a = qz[w4];
            v[w4 * 4 + 0] += a.x; v[w4 * 4 + 1] += a.y;
            v[w4 * 4 + 2] += a.z; v[w4 * 4 + 3] += a.w;
        }
    }

    f16x8 hv[2], lv[2];
#pragma unroll
    for (int h8 = 0; h8 < 2; ++h8)
#pragma unroll
        for (int e = 0; e < 8; ++e) {
            const float x = v[h8 * 8 + e];
            const f16 hh = (f16)x;
            hv[h8][e] = hh;
            lv[h8][e] = (f16)(x - (float)hh);
            th[lr][lc + h8 * 8 + e] = hh;
            tl[lr][lc + h8 * 8 + e] = lv[h8][e];
        }

    const size_t o = (size_t)(i * 256 + r0 + lr) * DDIM + j * 256 + c0 + lc;
    *(f16x8*)&hi[o] = hv[0]; *(f16x8*)&hi[o + 8] = hv[1];
    *(f16x8*)&lo[o] = lv[0]; *(f16x8*)&lo[o + 8] = lv[1];

    if (i > j) {
        __syncthreads();
        f16x8 thv[2], tlv[2];
#pragma unroll
        for (int h8 = 0; h8 < 2; ++h8)
#pragma unroll
            for (int e = 0; e < 8; ++e) {
                thv[h8][e] = th[lc + h8 * 8 + e][lr];
                tlv[h8][e] = tl[lc + h8 * 8 + e][lr];
            }
        const size_t od = (size_t)(j * 256 + c0 + lr) * DDIM + i * 256 + r0 + lc;
        *(f16x8*)&hi[od] = thv[0]; *(f16x8*)&hi[od + 8] = thv[1];
        *(f16x8*)&lo[od] = tlv[0]; *(f16x8*)&lo[od + 8] = tlv[1];
    }
}

// ---------------------------------------------------------------------------
// row softmax over sum of 4 fp32 partials (each rows x n): -> Z fp16
// ---------------------------------------------------------------------------
__global__ __launch_bounds__(256) void softmax_rows4(
    const float* __restrict__ S, f16* __restrict__ Z, int n)
{
    const int row = blockIdx.x;
    const int t = threadIdx.x;
    const int lane = t & 63, wv = t >> 6;
    const long ps = (long)DDIM * DDIM;
    const float* s = S + (size_t)row * n + t * 8;

    float x[8] = {};
#pragma unroll
    for (int q = 0; q < 4; ++q) {
        float4 a = ((const float4*)(s + q * ps))[0];
        float4 b = ((const float4*)(s + q * ps))[1];
        x[0] += a.x; x[1] += a.y; x[2] += a.z; x[3] += a.w;
        x[4] += b.x; x[5] += b.y; x[6] += b.z; x[7] += b.w;
    }

    float m = x[0];
#pragma unroll
    for (int j = 1; j < 8; ++j) m = fmaxf(m, x[j]);
    for (int o = 32; o; o >>= 1) m = fmaxf(m, __shfl_xor(m, o, 64));

    __shared__ float rmax[4], rsum[4];
    if (lane == 0) rmax[wv] = m;
    __syncthreads();
    m = fmaxf(fmaxf(rmax[0], rmax[1]), fmaxf(rmax[2], rmax[3]));

    float e[8], sum = 0.f;
#pragma unroll
    for (int j = 0; j < 8; ++j) { e[j] = expf(x[j] - m); sum += e[j]; }
    for (int o = 32; o; o >>= 1) sum += __shfl_xor(sum, o, 64);
    if (lane == 0) rsum[wv] = sum;
    __syncthreads();
    sum = rsum[0] + rsum[1] + rsum[2] + rsum[3];
    const float rs = 1.0f / sum;

    f16x8 z;
#pragma unroll
    for (int j = 0; j < 8; ++j) z[j] = (f16)(e[j] * rs);
    *(f16x8*)&Z[(size_t)row * n + t * 8] = z;
}

// ---------------------------------------------------------------------------
extern "C" void kernel_launch(void* const* d_in, const int* in_sizes, int n_in,
                              void* d_out, int out_size, void* d_ws, size_t ws_size,
                              hipStream_t stream)
{
    const float* X  = (const float*)d_in[0];  // (D, N)
    const float* Wq = (const float*)d_in[1];  // (D, D)
    const float* Wk = (const float*)d_in[2];  // (D, D)  -> V projection (ref swap)
    const float* Wv = (const float*)d_in[3];  // (D, D)  -> K projection (ref swap)
    float* out = (float*)d_out;
    char* ws = (char*)d_ws;

    const size_t MiB = 1024 * 1024;
    const size_t NEED = 184 * MiB;
    if (ws_size < NEED) return;  // diagnostic: output stays zero -> absmax == max|ref|

    // layout (MiB offsets), lifetimes:
    f16*   Xhi   = (f16*)(ws + 0 * MiB);     // dead after G-GEMM
    f16*   Xlo   = (f16*)(ws + 32 * MiB);    // dead after G-GEMM
    f16*   XhiT  = (f16*)(ws + 64 * MiB);    // live to the end (out-GEMM B)
    float* P     = (float*)(ws + 96 * MiB);  // [96,160): G tri partials (7x9MiB) / dense 4x16MiB
    f16*   Ghi   = (f16*)(ws + 160 * MiB);   // dead after M1-GEMM
    f16*   Glo   = (f16*)(ws + 168 * MiB);   // dead after M1-GEMM
    f16*   Z     = (f16*)(ws + 176 * MiB);
    // carved from dead X region after G-GEMM:
    f16*   Wqhi  = (f16*)(ws + 0 * MiB);
    f16*   Wqlo  = (f16*)(ws + 8 * MiB);
    f16*   Wvhi  = (f16*)(ws + 16 * MiB);
    f16*   Wvlo  = (f16*)(ws + 24 * MiB);
    f16*   Wkhi  = (f16*)(ws + 32 * MiB);
    f16*   WkhiT = (f16*)(ws + 40 * MiB);
    f16*   M1hi  = (f16*)(ws + 48 * MiB);
    f16*   M1lo  = (f16*)(ws + 56 * MiB);
    f16*   ZWkhi = (f16*)(ws + 0 * MiB);     // reuses Wqhi (dead after M1-GEMM)

    const float scale = 0.022097086912079608f;  // 1/sqrt(2048)
    const long n4W = (long)DDIM * DDIM / 4;

    // split X + transpose fused (writes Xhi, Xlo, XhiT in one pass)
    split_xt<<<dim3(NDIM / 64, DDIM / 64), 256, 0, stream>>>(
        X, Xhi, Xlo, XhiT, DDIM, NDIM);

    // G = X X^T lower triangle: 36 256^2 tiles x 7 uneven K-slices = 252 blocks
    gemm8_split<true><<<dim3(NTRI8, 1, 7), 512, 0, stream>>>(
        Xhi, Xlo, Xhi, Xlo, P, DDIM, DDIM, NDIM, 0);
    // reduce partials + symmetrize in one pass
    reduce7s<<<dim3(16, NTRI8), 256, 0, stream>>>(P, Ghi, Glo);

    // W splits (X regions now dead): Wq+Wv merged launch; Wk split+transpose
    split_w2<<<dim3(2 * n4W / 256), 256, 0, stream>>>(
        Wq, Wv, Wqhi, Wqlo, Wvhi, Wvlo, n4W);
    split_xt<<<dim3(DDIM / 64, DDIM / 64), 256, 0, stream>>>(
        Wk, Wkhi, (f16*)nullptr, WkhiT, DDIM, DDIM);

    // M1 = Wq G (G symmetric -> NT works), fused split, split-K x4
    gemm8_split<false><<<dim3(8, 8, 4), 512, 0, stream>>>(
        Wqhi, Wqlo, Ghi, Glo, P, DDIM, DDIM, DDIM, DDIM / 4);
    reduce4_split<<<dim3(n4W / 256), 256, 0, stream>>>(P, M1hi, M1lo, n4W, scale);

    // S = (M1*scale) Wv^T, fused split, split-K x4 (softmax consumes partials)
    gemm8_split<false><<<dim3(8, 8, 4), 512, 0, stream>>>(
        M1hi, M1lo, Wvhi, Wvlo, P, DDIM, DDIM, DDIM, DDIM / 4);
    softmax_rows4<<<dim3(DDIM), 256, 0, stream>>>(P, Z, DDIM);

    // ZWk = Z Wk (NT with B = Wk^T), split-K x4, then collapse to fp16
    gemm8_nt<<<dim3(8, 8, 4), 512, 0, stream>>>(
        Z, WkhiT, P, DDIM, DDIM, DDIM, DDIM / 4);
    reduce4_split<<<dim3(n4W / 256), 256, 0, stream>>>(P, ZWkhi, (f16*)nullptr, n4W, 1.0f);

    // out = (Z Wk) X  (NT: A=ZWkhi (D x D), B=XhiT (N x D))
    gemm8_nt<<<dim3(32, 8, 1), 512, 0, stream>>>(
        ZWkhi, XhiT, out, DDIM, NDIM, DDIM, DDIM);
}

// Round 13
// 411.129 us; speedup vs baseline: 1.0070x; 1.0070x over previous
//
#include <hip/hip_runtime.h>
#include <math.h>

#define DDIM 2048
#define NDIM 8192
#define NTRI8 36   // lower-triangle 256x256 tiles of the 2048x2048 G (8x8 grid)

typedef _Float16 f16;
typedef _Float16 f16x8 __attribute__((ext_vector_type(8)));
typedef _Float16 f16x4 __attribute__((ext_vector_type(4)));
typedef float    f32x4 __attribute__((ext_vector_type(4)));

#define MFMA16(a, b, c) __builtin_amdgcn_mfma_f32_16x16x32_f16(a, b, c, 0, 0, 0)

__device__ __forceinline__ void gload_lds16(const f16* g, f16* l) {
    __builtin_amdgcn_global_load_lds(
        (__attribute__((address_space(1))) const void*)g,
        (__attribute__((address_space(3))) void*)l, 16, 0, 0);
}

// raw barrier (NOT __syncthreads: avoids compiler-inserted vmcnt(0) drain)
#define SBAR() do { __builtin_amdgcn_sched_barrier(0); \
                    __builtin_amdgcn_s_barrier();      \
                    __builtin_amdgcn_sched_barrier(0); } while (0)
#define VMCNT0() asm volatile("s_waitcnt vmcnt(0)" ::: "memory")
#define VMCNT2() asm volatile("s_waitcnt vmcnt(2)" ::: "memory")
#define VMCNT4() asm volatile("s_waitcnt vmcnt(4)" ::: "memory")
#define VMCNT8() asm volatile("s_waitcnt vmcnt(8)" ::: "memory")

// bijective XCD-chunk swizzle (m204): n may be non-multiple of 8
__device__ __forceinline__ int xcd_swz(int lin, int n) {
    const int xcd = lin & 7, pos = lin >> 3;
    const int q = n >> 3, r = n & 7;
    return (xcd < r ? xcd * (q + 1) : r * (q + 1) + (xcd - r) * q) + pos;
}

// ---------------------------------------------------------------------------
// T2 bank-conflict swizzle for the [256 rows][32 f16] LDS unit (64 B rows).
// VALIDATED ONLY for the 16x16-MFMA read pattern (R3..R12: 0 conflicts).
// Session failure ledger (do not retry): 3-phase reorder (R1, -2x dense);
// intra-wave read hoist (R4, spill); 32x32 MFMA (R5, +4cyc/read bank
// conflict); 128^2 tile @2blk/CU (R8, reuse halves -> HBM-bound); forced
// read-cluster w/ sched fence (R12, compiler defeats, VGPR stays 128).
// Wins kept: ah-live P3 TRI / a2-reread dense (R2/R3 A/B); relaxed barriers
// 8->2 per tile (R10, -5us/TRI); (512,1) launch bound (R11, neutral-free).
// ---------------------------------------------------------------------------
__device__ __forceinline__ int swz(int R, int fo8) {
    return R * 32 + (fo8 ^ (((R >> 1) & 3) << 3));
}

// stage one 16 KiB unit (256 rows x 32 k-elems, f16) global -> LDS.
// 2 vmem ops per thread. LDS dest linear; source k-slot pre-swizzled.
__device__ __forceinline__ void stage_unit(
    const f16* __restrict__ g, int grow0, size_t kelem, int Ktot,
    f16* ldsbase, int tid)
{
#pragma unroll
    for (int i = 0; i < 2; ++i) {
        const int c = tid + i * 512;
        const int row  = c >> 2;
        const int slot = (c & 3) ^ ((c >> 3) & 3);   // (c&3) ^ ((row>>1)&3)
        gload_lds16(g + (size_t)(grow0 + row) * Ktot + kelem + slot * 8,
                    ldsbase + c * 8);
    }
}

// ---------------------------------------------------------------------------
// K2 (R13 = R11 exact): 256x256 FUSED split-fp16 NT GEMM, relaxed-barrier
// schedule (2 vmcnt-anchored barriers/K-tile) + launch_bounds(512,1).
// Ledger (R10 audit):
//  * P2-end vmcnt(8)+SBAR covers Bl(u) for P3; gates P3's al(u) overwrite.
//  * P3-end vmcnt(4)+SBAR covers Ah/Bh/Al(u+1) for the next tile.
//   C_z += Ah Bh^T + Al Bh^T + Ah Bl^T.  BK=32; units 16 KiB; dbuf 64 KiB.
//   TRI P3: ah live from P0. dense P3: a2 re-read (R2/R3 A/B result).
// Measured (R11): TRI 96.0-96.5us, MfmaUtil 53-55, 0 bank conflicts.
// ---------------------------------------------------------------------------
template <bool TRI>
__global__ __launch_bounds__(512, 1) void gemm8_split(
    const f16* __restrict__ Ah_g, const f16* __restrict__ Al_g,
    const f16* __restrict__ Bh_g, const f16* __restrict__ Bl_g,
    float* __restrict__ C, int Mrows, int Ncols, int Ktot, int Kchunk)
{
    __shared__ f16 lds[65536];   // 128 KiB

    const int tid  = threadIdx.x;
    const int lane = tid & 63;
    const int w    = tid >> 6;
    const int wr   = w >> 2;          // 0..1
    const int wc   = w & 3;           // 0..3
    const int ln15 = lane & 15;
    const int fo8  = (lane >> 4) * 8;

    int row0, col0, nkt;
    size_t kbeg;
    if constexpr (TRI) {
        const int t = xcd_swz(blockIdx.x, NTRI8);
        int i = 0;
        while ((i + 1) * (i + 2) / 2 <= t) ++i;
        const int j = t - i * (i + 1) / 2;
        row0 = i * 256; col0 = j * 256;
        const int z = blockIdx.z;                       // 0..6, uneven chunks
        const int kb_u = z * 37 - (z > 4 ? z - 4 : 0);  // 37,37,37,37,36,36,36
        nkt = (z < 4) ? 37 : 36;
        kbeg = (size_t)kb_u * 32;
        C += ((size_t)z * NTRI8 + t) * (256 * 256);     // compact partial
    } else {
        const int s = xcd_swz(blockIdx.y * gridDim.x + blockIdx.x,
                              gridDim.x * gridDim.y);
        row0 = (s / gridDim.x) * 256;
        col0 = (s % gridDim.x) * 256;
        nkt  = Kchunk / 32;
        kbeg = (size_t)blockIdx.z * Kchunk;
        C += (size_t)blockIdx.z * Mrows * Ncols;
    }

    f32x4 acc[8][4] = {};

    // prologue: tile0's 4 units + Al(1); drain; barrier
    stage_unit(Ah_g, row0, kbeg, Ktot, lds + 0,     tid);
    stage_unit(Al_g, row0, kbeg, Ktot, lds + 8192,  tid);
    stage_unit(Bh_g, col0, kbeg, Ktot, lds + 16384, tid);
    stage_unit(Bl_g, col0, kbeg, Ktot, lds + 24576, tid);
    if (nkt > 1)
        stage_unit(Al_g, row0, kbeg + 32, Ktot, lds + 32768 + 8192, tid);
    VMCNT0();
    SBAR();

    for (int u = 0; u < nkt; ++u) {
        const int cur = (u & 1) * 32768, nxt = ((u + 1) & 1) * 32768;
        const size_t ku = kbeg + (size_t)u * 32;
        f16x8 ah[8], bh[4];

        // ---- P0: HH, n-half 0 (no barrier) ----
#pragma unroll
        for (int m = 0; m < 8; ++m)
            ah[m] = *(const f16x8*)&lds[cur + swz(wr * 128 + m * 16 + ln15, fo8)];
        bh[0] = *(const f16x8*)&lds[cur + 16384 + swz(wc * 64 +  0 + ln15, fo8)];
        bh[1] = *(const f16x8*)&lds[cur + 16384 + swz(wc * 64 + 16 + ln15, fo8)];
        if (u + 1 < nkt) stage_unit(Bh_g, col0, ku + 32, Ktot, lds + nxt + 16384, tid);
        __builtin_amdgcn_s_setprio(1);
#pragma unroll
        for (int m = 0; m < 8; ++m) {
            acc[m][0] = MFMA16(ah[m], bh[0], acc[m][0]);
            acc[m][1] = MFMA16(ah[m], bh[1], acc[m][1]);
        }
        __builtin_amdgcn_s_setprio(0);

        // ---- P1: HH, n-half 1 (no barrier) ----
        bh[2] = *(const f16x8*)&lds[cur + 16384 + swz(wc * 64 + 32 + ln15, fo8)];
        bh[3] = *(const f16x8*)&lds[cur + 16384 + swz(wc * 64 + 48 + ln15, fo8)];
        if (u + 1 < nkt) stage_unit(Ah_g, row0, ku + 32, Ktot, lds + nxt + 0, tid);
        __builtin_amdgcn_s_setprio(1);
#pragma unroll
        for (int m = 0; m < 8; ++m) {
            acc[m][2] = MFMA16(ah[m], bh[2], acc[m][2]);
            acc[m][3] = MFMA16(ah[m], bh[3], acc[m][3]);
        }
        __builtin_amdgcn_s_setprio(0);

        // ---- P2: LH, all n ----
        {
            f16x8 al[8];
#pragma unroll
            for (int m = 0; m < 8; ++m)
                al[m] = *(const f16x8*)&lds[cur + 8192 + swz(wr * 128 + m * 16 + ln15, fo8)];
            if (u + 1 < nkt) stage_unit(Bl_g, col0, ku + 32, Ktot, lds + nxt + 24576, tid);
            __builtin_amdgcn_s_setprio(1);
#pragma unroll
            for (int m = 0; m < 8; ++m)
#pragma unroll
                for (int n = 0; n < 4; ++n)
                    acc[m][n] = MFMA16(al[m], bh[n], acc[m][n]);
            __builtin_amdgcn_s_setprio(0);
        }
        if (u == nkt - 1) { VMCNT0(); } else { VMCNT8(); }
        SBAR();   // KEPT: covers Bl(u) for P3 reads; gates P3's al overwrite

        // ---- P3: HL, all n ----
        if constexpr (TRI) {
            // ah LIVE from P0; no re-read (24 ds_reads/tile)
            f16x8 bl[4];
#pragma unroll
            for (int n = 0; n < 4; ++n)
                bl[n] = *(const f16x8*)&lds[cur + 24576 + swz(wc * 64 + n * 16 + ln15, fo8)];
            if (u + 2 < nkt) stage_unit(Al_g, row0, ku + 64, Ktot, lds + cur + 8192, tid);
            __builtin_amdgcn_s_setprio(1);
#pragma unroll
            for (int m = 0; m < 8; ++m)
#pragma unroll
                for (int n = 0; n < 4; ++n)
                    acc[m][n] = MFMA16(ah[m], bl[n], acc[m][n]);
            __builtin_amdgcn_s_setprio(0);
        } else {
            // dense: a2 re-read (caps register pressure)
            f16x8 a2[8], bl[4];
#pragma unroll
            for (int m = 0; m < 8; ++m)
                a2[m] = *(const f16x8*)&lds[cur + swz(wr * 128 + m * 16 + ln15, fo8)];
#pragma unroll
            for (int n = 0; n < 4; ++n)
                bl[n] = *(const f16x8*)&lds[cur + 24576 + swz(wc * 64 + n * 16 + ln15, fo8)];
            if (u + 2 < nkt) stage_unit(Al_g, row0, ku + 64, Ktot, lds + cur + 8192, tid);
            __builtin_amdgcn_s_setprio(1);
#pragma unroll
            for (int m = 0; m < 8; ++m)
#pragma unroll
                for (int n = 0; n < 4; ++n)
                    acc[m][n] = MFMA16(a2[m], bl[n], acc[m][n]);
            __builtin_amdgcn_s_setprio(0);
        }
        if (u < nkt - 2) { VMCNT4(); }
        else if (u == nkt - 2) { VMCNT2(); }
        SBAR();   // KEPT: tile boundary; covers Ah/Bh/Al(u+1) for next tile
    }

    // epilogue: C/D layout col=lane&15, row=(lane>>4)*4+reg [m89-verified]
    const int rsub = (lane >> 4) * 4;
#pragma unroll
    for (int m = 0; m < 8; ++m)
#pragma unroll
        for (int n = 0; n < 4; ++n)
#pragma unroll
            for (int r = 0; r < 4; ++r) {
                const int cr = wr * 128 + m * 16 + rsub + r;
                const int cc = wc * 64 + n * 16 + ln15;
                if constexpr (TRI)
                    C[(size_t)cr * 256 + cc] = acc[m][n][r];
                else
                    C[(size_t)(row0 + cr) * Ncols + col0 + cc] = acc[m][n][r];
            }
}

// ---------------------------------------------------------------------------
// K1 (R13 = R11 exact): 256x256 single-product NT GEMM, BK=64, relaxed
// barriers (p1-end vmcnt4, p3-end vmcnt4) + launch_bounds(512,1).
// ---------------------------------------------------------------------------
__global__ __launch_bounds__(512, 1) void gemm8_nt(
    const f16* __restrict__ A_g, const f16* __restrict__ B_g,
    float* __restrict__ C, int Mrows, int Ncols, int Ktot, int Kchunk)
{
    __shared__ f16 lds[65536];

    const int tid  = threadIdx.x;
    const int lane = tid & 63;
    const int w    = tid >> 6;
    const int wr   = w >> 2;
    const int wc   = w & 3;
    const int ln15 = lane & 15;
    const int fo8  = (lane >> 4) * 8;

    const int s = xcd_swz(blockIdx.y * gridDim.x + blockIdx.x,
                          gridDim.x * gridDim.y);
    const int row0 = (s / gridDim.x) * 256;
    const int col0 = (s % gridDim.x) * 256;
    const int nkt  = Kchunk / 64;
    const size_t kbeg = (size_t)blockIdx.z * Kchunk;
    C += (size_t)blockIdx.z * Mrows * Ncols;

    f32x4 acc[8][4] = {};

    stage_unit(A_g, row0, kbeg,      Ktot, lds + 0,     tid);  // Ak0(0)
    stage_unit(B_g, col0, kbeg,      Ktot, lds + 16384, tid);  // Bk0(0)
    stage_unit(A_g, row0, kbeg + 32, Ktot, lds + 8192,  tid);  // Ak1(0)
    stage_unit(B_g, col0, kbeg + 32, Ktot, lds + 24576, tid);  // Bk1(0)
    VMCNT0();
    SBAR();

    for (int u = 0; u < nkt; ++u) {
        const int cur = (u & 1) * 32768, nxt = ((u + 1) & 1) * 32768;
        const size_t ku = kbeg + (size_t)u * 64;
        f16x8 a[8], b0, b1;

        // ---- p0: ks0, n-half 0 (no barrier) ----
#pragma unroll
        for (int m = 0; m < 8; ++m)
            a[m] = *(const f16x8*)&lds[cur + swz(wr * 128 + m * 16 + ln15, fo8)];
        b0 = *(const f16x8*)&lds[cur + 16384 + swz(wc * 64 +  0 + ln15, fo8)];
        b1 = *(const f16x8*)&lds[cur + 16384 + swz(wc * 64 + 16 + ln15, fo8)];
        if (u + 1 < nkt) stage_unit(A_g, row0, ku + 64, Ktot, lds + nxt + 0, tid);
        __builtin_amdgcn_s_setprio(1);
#pragma unroll
        for (int m = 0; m < 8; ++m) {
            acc[m][0] = MFMA16(a[m], b0, acc[m][0]);
            acc[m][1] = MFMA16(a[m], b1, acc[m][1]);
        }
        __builtin_amdgcn_s_setprio(0);

        // ---- p1: ks0, n-half 1 ----
        b0 = *(const f16x8*)&lds[cur + 16384 + swz(wc * 64 + 32 + ln15, fo8)];
        b1 = *(const f16x8*)&lds[cur + 16384 + swz(wc * 64 + 48 + ln15, fo8)];
        if (u + 1 < nkt) stage_unit(B_g, col0, ku + 64, Ktot, lds + nxt + 16384, tid);
        __builtin_amdgcn_s_setprio(1);
#pragma unroll
        for (int m = 0; m < 8; ++m) {
            acc[m][2] = MFMA16(a[m], b0, acc[m][2]);
            acc[m][3] = MFMA16(a[m], b1, acc[m][3]);
        }
        __builtin_amdgcn_s_setprio(0);
        if (u == nkt - 1) { VMCNT0(); } else { VMCNT4(); }
        SBAR();   // KEPT: covers Ak1/Bk1(u) for p2/p3 reads

        // ---- p2: ks1, n-half 0 (no barrier) ----
#pragma unroll
        for (int m = 0; m < 8; ++m)
            a[m] = *(const f16x8*)&lds[cur + 8192 + swz(wr * 128 + m * 16 + ln15, fo8)];
        b0 = *(const f16x8*)&lds[cur + 24576 + swz(wc * 64 +  0 + ln15, fo8)];
        b1 = *(const f16x8*)&lds[cur + 24576 + swz(wc * 64 + 16 + ln15, fo8)];
        if (u + 1 < nkt) stage_unit(A_g, row0, ku + 96, Ktot, lds + nxt + 8192, tid);
        __builtin_amdgcn_s_setprio(1);
#pragma unroll
        for (int m = 0; m < 8; ++m) {
            acc[m][0] = MFMA16(a[m], b0, acc[m][0]);
            acc[m][1] = MFMA16(a[m], b1, acc[m][1]);
        }
        __builtin_amdgcn_s_setprio(0);

        // ---- p3: ks1, n-half 1 ----
        b0 = *(const f16x8*)&lds[cur + 24576 + swz(wc * 64 + 32 + ln15, fo8)];
        b1 = *(const f16x8*)&lds[cur + 24576 + swz(wc * 64 + 48 + ln15, fo8)];
        if (u + 1 < nkt) stage_unit(B_g, col0, ku + 96, Ktot, lds + nxt + 24576, tid);
        __builtin_amdgcn_s_setprio(1);
#pragma unroll
        for (int m = 0; m < 8; ++m) {
            acc[m][2] = MFMA16(a[m], b0, acc[m][2]);
            acc[m][3] = MFMA16(a[m], b1, acc[m][3]);
        }
        __builtin_amdgcn_s_setprio(0);
        if (u < nkt - 1) { VMCNT4(); }
        SBAR();   // KEPT: tile boundary; covers Ak0/Bk0(u+1)
    }

    const int rsub = (lane >> 4) * 4;
#pragma unroll
    for (int m = 0; m < 8; ++m)
#pragma unroll
        for (int n = 0; n < 4; ++n)
#pragma unroll
            for (int r = 0; r < 4; ++r)
                C[(size_t)(row0 + wr * 128 + m * 16 + rsub + r) * Ncols
                  + col0 + wc * 64 + n * 16 + ln15] = acc[m][n][r];
}

// ---------------------------------------------------------------------------
// split BOTH W matrices fp32 -> fp16 hi/lo in one launch
// ---------------------------------------------------------------------------
__global__ __launch_bounds__(256) void split_w2(
    const float* __restrict__ A, const float* __restrict__ B,
    f16* __restrict__ Ahi, f16* __restrict__ Alo,
    f16* __restrict__ Bhi, f16* __restrict__ Blo, long n4)
{
    long i = (long)blockIdx.x * 256 + threadIdx.x;
    const float* src;
    f16 *hi, *lo;
    long k;
    if (i < n4) { src = A; hi = Ahi; lo = Alo; k = i; }
    else        { src = B; hi = Bhi; lo = Blo; k = i - n4; }
    float4 x = ((const float4*)src)[k];
    float a = x.x, b = x.y, c = x.z, d = x.w;
    f16x4 h;
    h[0] = (f16)a; h[1] = (f16)b; h[2] = (f16)c; h[3] = (f16)d;
    ((f16x4*)hi)[k] = h;
    f16x4 l;
    l[0] = (f16)(a - (float)h[0]);
    l[1] = (f16)(b - (float)h[1]);
    l[2] = (f16)(c - (float)h[2]);
    l[3] = (f16)(d - (float)h[3]);
    ((f16x4*)lo)[k] = l;
}

// ---------------------------------------------------------------------------
// fused split fp32 -> f16 hi/lo (row-major) + hi^T, 64x64 tiles.
// ---------------------------------------------------------------------------
__global__ __launch_bounds__(256) void split_xt(
    const float* __restrict__ in, f16* __restrict__ hi, f16* __restrict__ lo,
    f16* __restrict__ hiT, int rows, int cols)
{
    __shared__ f16 tile[64][72];
    const int c0 = blockIdx.x * 64;
    const int r0 = blockIdx.y * 64;
    const int t = threadIdx.x;
    const int lr = t >> 3;      // 0..31
    const int lc8 = t & 7;      // 0..7
#pragma unroll
    for (int h = 0; h < 2; ++h) {
        const int r = lr + h * 32;
        const float* src = &in[(size_t)(r0 + r) * cols + c0 + lc8 * 8];
        float4 a = ((const float4*)src)[0];
        float4 b = ((const float4*)src)[1];
        float v[8] = {a.x, a.y, a.z, a.w, b.x, b.y, b.z, b.w};
        f16x8 hv, lv;
#pragma unroll
        for (int j = 0; j < 8; ++j) {
            hv[j] = (f16)v[j];
            lv[j] = (f16)(v[j] - (float)hv[j]);
        }
        *(f16x8*)&hi[(size_t)(r0 + r) * cols + c0 + lc8 * 8] = hv;
        if (lo != nullptr)
            *(f16x8*)&lo[(size_t)(r0 + r) * cols + c0 + lc8 * 8] = lv;
#pragma unroll
        for (int j = 0; j < 8; ++j) tile[r][lc8 * 8 + j] = hv[j];
    }
    __syncthreads();
#pragma unroll
    for (int h = 0; h < 2; ++h) {
        const int c = lr + h * 32;
        f16x8 v;
#pragma unroll
        for (int j = 0; j < 8; ++j) v[j] = tile[lc8 * 8 + j][c];
        *(f16x8*)&hiT[(size_t)(c0 + c) * rows + r0 + lc8 * 8] = v;
    }
}

// ---------------------------------------------------------------------------
// reduce 4 contiguous fp32 partials -> fp16 hi/lo (lo may be null), scaled
// ---------------------------------------------------------------------------
__global__ __launch_bounds__(256) void reduce4_split(
    const float* __restrict__ P, f16* __restrict__ hi, f16* __restrict__ lo,
    long n4, float scale)
{
    long i = (long)blockIdx.x * 256 + threadIdx.x;
    if (i >= n4) return;
    const float4* p = (const float4*)P;
    float4 a = p[i], b = p[i + n4], c = p[i + 2 * n4], d = p[i + 3 * n4];
    float v0 = ((a.x + b.x) + (c.x + d.x)) * scale;
    float v1 = ((a.y + b.y) + (c.y + d.y)) * scale;
    float v2 = ((a.z + b.z) + (c.z + d.z)) * scale;
    float v3 = ((a.w + b.w) + (c.w + d.w)) * scale;
    f16x4 h;
    h[0] = (f16)v0; h[1] = (f16)v1; h[2] = (f16)v2; h[3] = (f16)v3;
    ((f16x4*)hi)[i] = h;
    if (lo != nullptr) {
        f16x4 l;
        l[0] = (f16)(v0 - (float)h[0]);
        l[1] = (f16)(v1 - (float)h[1]);
        l[2] = (f16)(v2 - (float)h[2]);
        l[3] = (f16)(v3 - (float)h[3]);
        ((f16x4*)lo)[i] = l;
    }
}

// ---------------------------------------------------------------------------
// reduce 7 compact 256x256 triangle partials -> Ghi/Glo at tile (i,j)
// AND mirror to (j,i) when i>j (fused symm). grid (16, NTRI8): block = one
// 64x64 subtile (4x4 per 256-tile); LDS transpose for the mirror.
// ---------------------------------------------------------------------------
__global__ __launch_bounds__(256) void reduce7s(
    const float* __restrict__ P, f16* __restrict__ hi, f16* __restrict__ lo)
{
    const int t = blockIdx.y;
    int i = 0;
    while ((i + 1) * (i + 2) / 2 <= t) ++i;
    const int j = t - i * (i + 1) / 2;
    const int r0 = (blockIdx.x >> 2) * 64;   // subtile origin within 256-tile
    const int c0 = (blockIdx.x & 3) * 64;

    const int tid = threadIdx.x;
    const int lr = tid >> 2;                 // 0..63
    const int lc = (tid & 3) * 16;           // 0,16,32,48

    const long zs = (long)NTRI8 * (256 * 256);  // slice stride (floats)
    const float* q = P + (long)t * (256 * 256)
                   + (size_t)(r0 + lr) * 256 + c0 + lc;

    __shared__ f16 th[64][72], tl[64][72];

    float v[16];
#pragma unroll
    for (int e = 0; e < 16; ++e) v[e] = 0.f;
#pragma unroll
    for (int z = 0; z < 7; ++z) {
        const float4* qz = (const float4*)(q + z * zs);
#pragma unroll
        for (int w4 = 0; w4 < 4; ++w4) {
            float4 a = qz[w4];
            v[w4 * 4 + 0] += a.x; v[w4 * 4 + 1] += a.y;
            v[w4 * 4 + 2] += a.z; v[w4 * 4 + 3] += a.w;
        }
    }

    f16x8 hv[2], lv[2];
#pragma unroll
    for (int h8 = 0; h8 < 2; ++h8)
#pragma unroll
        for (int e = 0; e < 8; ++e) {
            const float x = v[h8 * 8 + e];
            const f16 hh = (f16)x;
            hv[h8][e] = hh;
            lv[h8][e] = (f16)(x - (float)hh);
            th[lr][lc + h8 * 8 + e] = hh;
            tl[lr][lc + h8 * 8 + e] = lv[h8][e];
        }

    const size_t o = (size_t)(i * 256 + r0 + lr) * DDIM + j * 256 + c0 + lc;
    *(f16x8*)&hi[o] = hv[0]; *(f16x8*)&hi[o + 8] = hv[1];
    *(f16x8*)&lo[o] = lv[0]; *(f16x8*)&lo[o + 8] = lv[1];

    if (i > j) {
        __syncthreads();
        f16x8 thv[2], tlv[2];
#pragma unroll
        for (int h8 = 0; h8 < 2; ++h8)
#pragma unroll
            for (int e = 0; e < 8; ++e) {
                thv[h8][e] = th[lc + h8 * 8 + e][lr];
                tlv[h8][e] = tl[lc + h8 * 8 + e][lr];
            }
        const size_t od = (size_t)(j * 256 + c0 + lr) * DDIM + i * 256 + r0 + lc;
        *(f16x8*)&hi[od] = thv[0]; *(f16x8*)&hi[od + 8] = thv[1];
        *(f16x8*)&lo[od] = tlv[0]; *(f16x8*)&lo[od + 8] = tlv[1];
    }
}

// ---------------------------------------------------------------------------
// row softmax over sum of 4 fp32 partials (each rows x n): -> Z fp16
// ---------------------------------------------------------------------------
__global__ __launch_bounds__(256) void softmax_rows4(
    const float* __restrict__ S, f16* __restrict__ Z, int n)
{
    const int row = blockIdx.x;
    const int t = threadIdx.x;
    const int lane = t & 63, wv = t >> 6;
    const long ps = (long)DDIM * DDIM;
    const float* s = S + (size_t)row * n + t * 8;

    float x[8] = {};
#pragma unroll
    for (int q = 0; q < 4; ++q) {
        float4 a = ((const float4*)(s + q * ps))[0];
        float4 b = ((const float4*)(s + q * ps))[1];
        x[0] += a.x; x[1] += a.y; x[2] += a.z; x[3] += a.w;
        x[4] += b.x; x[5] += b.y; x[6] += b.z; x[7] += b.w;
    }

    float m = x[0];
#pragma unroll
    for (int j = 1; j < 8; ++j) m = fmaxf(m, x[j]);
    for (int o = 32; o; o >>= 1) m = fmaxf(m, __shfl_xor(m, o, 64));

    __shared__ float rmax[4], rsum[4];
    if (lane == 0) rmax[wv] = m;
    __syncthreads();
    m = fmaxf(fmaxf(rmax[0], rmax[1]), fmaxf(rmax[2], rmax[3]));

    float e[8], sum = 0.f;
#pragma unroll
    for (int j = 0; j < 8; ++j) { e[j] = expf(x[j] - m); sum += e[j]; }
    for (int o = 32; o; o >>= 1) sum += __shfl_xor(sum, o, 64);
    if (lane == 0) rsum[wv] = sum;
    __syncthreads();
    sum = rsum[0] + rsum[1] + rsum[2] + rsum[3];
    const float rs = 1.0f / sum;

    f16x8 z;
#pragma unroll
    for (int j = 0; j < 8; ++j) z[j] = (f16)(e[j] * rs);
    *(f16x8*)&Z[(size_t)row * n + t * 8] = z;
}

// ---------------------------------------------------------------------------
extern "C" void kernel_launch(void* const* d_in, const int* in_sizes, int n_in,
                              void* d_out, int out_size, void* d_ws, size_t ws_size,
                              hipStream_t stream)
{
    const float* X  = (const float*)d_in[0];  // (D, N)
    const float* Wq = (const float*)d_in[1];  // (D, D)
    const float* Wk = (const float*)d_in[2];  // (D, D)  -> V projection (ref swap)
    const float* Wv = (const float*)d_in[3];  // (D, D)  -> K projection (ref swap)
    float* out = (float*)d_out;
    char* ws = (char*)d_ws;

    const size_t MiB = 1024 * 1024;
    const size_t NEED = 184 * MiB;
    if (ws_size < NEED) return;  // diagnostic: output stays zero -> absmax == max|ref|

    // layout (MiB offsets), lifetimes:
    f16*   Xhi   = (f16*)(ws + 0 * MiB);     // dead after G-GEMM
    f16*   Xlo   = (f16*)(ws + 32 * MiB);    // dead after G-GEMM
    f16*   XhiT  = (f16*)(ws + 64 * MiB);    // live to the end (out-GEMM B)
    float* P     = (float*)(ws + 96 * MiB);  // [96,160): G tri partials (7x9MiB) / dense 4x16MiB
    f16*   Ghi   = (f16*)(ws + 160 * MiB);   // dead after M1-GEMM
    f16*   Glo   = (f16*)(ws + 168 * MiB);   // dead after M1-GEMM
    f16*   Z     = (f16*)(ws + 176 * MiB);
    // carved from dead X region after G-GEMM:
    f16*   Wqhi  = (f16*)(ws + 0 * MiB);
    f16*   Wqlo  = (f16*)(ws + 8 * MiB);
    f16*   Wvhi  = (f16*)(ws + 16 * MiB);
    f16*   Wvlo  = (f16*)(ws + 24 * MiB);
    f16*   Wkhi  = (f16*)(ws + 32 * MiB);
    f16*   WkhiT = (f16*)(ws + 40 * MiB);
    f16*   M1hi  = (f16*)(ws + 48 * MiB);
    f16*   M1lo  = (f16*)(ws + 56 * MiB);
    f16*   ZWkhi = (f16*)(ws + 0 * MiB);     // reuses Wqhi (dead after M1-GEMM)

    const float scale = 0.022097086912079608f;  // 1/sqrt(2048)
    const long n4W = (long)DDIM * DDIM / 4;

    // split X + transpose fused (writes Xhi, Xlo, XhiT in one pass)
    split_xt<<<dim3(NDIM / 64, DDIM / 64), 256, 0, stream>>>(
        X, Xhi, Xlo, XhiT, DDIM, NDIM);

    // G = X X^T lower triangle: 36 256^2 tiles x 7 uneven K-slices = 252 blocks
    gemm8_split<true><<<dim3(NTRI8, 1, 7), 512, 0, stream>>>(
        Xhi, Xlo, Xhi, Xlo, P, DDIM, DDIM, NDIM, 0);
    // reduce partials + symmetrize in one pass
    reduce7s<<<dim3(16, NTRI8), 256, 0, stream>>>(P, Ghi, Glo);

    // W splits (X regions now dead): Wq+Wv merged launch; Wk split+transpose
    split_w2<<<dim3(2 * n4W / 256), 256, 0, stream>>>(
        Wq, Wv, Wqhi, Wqlo, Wvhi, Wvlo, n4W);
    split_xt<<<dim3(DDIM / 64, DDIM / 64), 256, 0, stream>>>(
        Wk, Wkhi, (f16*)nullptr, WkhiT, DDIM, DDIM);

    // M1 = Wq G (G symmetric -> NT works), fused split, split-K x4
    gemm8_split<false><<<dim3(8, 8, 4), 512, 0, stream>>>(
        Wqhi, Wqlo, Ghi, Glo, P, DDIM, DDIM, DDIM, DDIM / 4);
    reduce4_split<<<dim3(n4W / 256), 256, 0, stream>>>(P, M1hi, M1lo, n4W, scale);

    // S = (M1*scale) Wv^T, fused split, split-K x4 (softmax consumes partials)
    gemm8_split<false><<<dim3(8, 8, 4), 512, 0, stream>>>(
        M1hi, M1lo, Wvhi, Wvlo, P, DDIM, DDIM, DDIM, DDIM / 4);
    softmax_rows4<<<dim3(DDIM), 256, 0, stream>>>(P, Z, DDIM);

    // ZWk = Z Wk (NT with B = Wk^T), split-K x4, then collapse to fp16
    gemm8_nt<<<dim3(8, 8, 4), 512, 0, stream>>>(
        Z, WkhiT, P, DDIM, DDIM, DDIM, DDIM / 4);
    reduce4_split<<<dim3(n4W / 256), 256, 0, stream>>>(P, ZWkhi, (f16*)nullptr, n4W, 1.0f);

    // out = (Z Wk) X  (NT: A=ZWkhi (D x D), B=XhiT (N x D))
    gemm8_nt<<<dim3(32, 8, 1), 512, 0, stream>>>(
        ZWkhi, XhiT, out, DDIM, NDIM, DDIM, DDIM);
}